// Round 3
// baseline (324.438 us; speedup 1.0000x reference)
//
#include <hip/hip_runtime.h>

typedef float        f32x4  __attribute__((ext_vector_type(4)));
typedef float        f32x16 __attribute__((ext_vector_type(16)));
typedef unsigned int u32x4  __attribute__((ext_vector_type(4)));
typedef unsigned int u32x2  __attribute__((ext_vector_type(2)));
typedef int          i32x2  __attribute__((ext_vector_type(2)));
typedef __bf16       bf16x8 __attribute__((ext_vector_type(8)));

#define DEVFN static __device__ __forceinline__

DEVFN unsigned short f2bf(float f){
  unsigned u = __builtin_bit_cast(unsigned, f);
  u += 0x7FFFu + ((u >> 16) & 1u);            // RNE
  return (unsigned short)(u >> 16);
}
DEVFN unsigned cvtpk(float a, float b){       // dst.lo=bf16(a), dst.hi=bf16(b)
  unsigned r;
  asm("v_cvt_pk_bf16_f32 %0, %1, %2" : "=v"(r) : "v"(a), "v"(b));
  return r;
}
DEVFN bf16x8 as_bf(u32x4 v){ union{u32x4 u; bf16x8 b;} x; x.u=v; return x.b; }

// x' = {x.lo31, y.lo31}; y' = {x.hi31, y.hi31}
DEVFN void plswap(unsigned &x, unsigned &y, int h){
#if __has_builtin(__builtin_amdgcn_permlane32_swap)
  i32x2 r = __builtin_amdgcn_permlane32_swap((int)x, (int)y, false, false);
  x = (unsigned)r[0]; y = (unsigned)r[1];
#else
  unsigned ox = (unsigned)__shfl_xor((int)x, 32);
  unsigned oy = (unsigned)__shfl_xor((int)y, 32);
  unsigned nx = h ? oy : x;
  unsigned ny = h ? y  : ox;
  x = nx; y = ny;
#endif
}

DEVFN void gload16(const char* src, char* lds){
  __builtin_amdgcn_global_load_lds(
      (__attribute__((address_space(1))) void*)src,
      (__attribute__((address_space(3))) void*)lds, 16, 0, 0);
}

constexpr int BB = 16, NQ = 2048, NK = 2048, F = 512, D = 256, FV = 512;

// ---------------- projection + row l2norm ---------------- (unchanged, known-good)
template<int KD, int ND, bool TR>
__global__ __launch_bounds__(256,2) void proj_kernel(const float* __restrict__ X,
                                                     const float* __restrict__ W,
                                                     unsigned short* __restrict__ Y)
{
  constexpr int NW = ND/4;
  constexpr int AF = TR ? 8 : 2;
  constexpr int BF = TR ? 2 : NW/16;
  __shared__ __align__(16) char xsm[32*80];
  __shared__ __align__(16) char wsm[ND*80];
  __shared__ float wsum[4][32];
  const int tid = threadIdx.x;
  const int lane = tid & 63;
  const int wid = tid >> 6;
  const int q16 = lane & 15;
  const int g = lane >> 4;
  const int row0 = blockIdx.x * 32;
  const int rX = tid >> 3, cX = (tid & 7) * 4;

  f32x4 z4 = {0.f,0.f,0.f,0.f};
  f32x4 acc[AF][BF];
  #pragma unroll
  for (int i=0;i<AF;i++){
    #pragma unroll
    for (int j=0;j<BF;j++) acc[i][j] = z4;
  }

  for (int k0 = 0; k0 < KD; k0 += 32){
    {
      f32x4 v = *(const f32x4*)(X + (size_t)(row0+rX)*KD + k0 + cX);
      u32x2 p; p[0]=cvtpk(v[0],v[1]); p[1]=cvtpk(v[2],v[3]);
      *(u32x2*)(xsm + rX*80 + cX*2) = p;
    }
    #pragma unroll
    for (int j=0;j<ND/32;j++){
      int r = j*32 + rX;
      f32x4 v = *(const f32x4*)(W + (size_t)r*KD + k0 + cX);
      u32x2 p; p[0]=cvtpk(v[0],v[1]); p[1]=cvtpk(v[2],v[3]);
      *(u32x2*)(wsm + r*80 + cX*2) = p;
    }
    __syncthreads();
    if constexpr (!TR){
      bf16x8 a[2], bb[BF];
      #pragma unroll
      for (int mi=0;mi<2;mi++)  a[mi]  = as_bf(*(const u32x4*)(xsm + (16*mi+q16)*80 + g*16));
      #pragma unroll
      for (int ni=0;ni<BF;ni++) bb[ni] = as_bf(*(const u32x4*)(wsm + (wid*NW + 16*ni + q16)*80 + g*16));
      #pragma unroll
      for (int mi=0;mi<2;mi++){
        #pragma unroll
        for (int ni=0;ni<BF;ni++)
          acc[mi][ni] = __builtin_amdgcn_mfma_f32_16x16x32_bf16(a[mi], bb[ni], acc[mi][ni], 0,0,0);
      }
    } else {
      bf16x8 a[8], bb[2];
      #pragma unroll
      for (int ai=0;ai<8;ai++) a[ai] = as_bf(*(const u32x4*)(wsm + (wid*NW + 16*ai + q16)*80 + g*16));
      #pragma unroll
      for (int ci=0;ci<2;ci++) bb[ci] = as_bf(*(const u32x4*)(xsm + (16*ci+q16)*80 + g*16));
      #pragma unroll
      for (int ai=0;ai<8;ai++){
        #pragma unroll
        for (int ci=0;ci<2;ci++)
          acc[ai][ci] = __builtin_amdgcn_mfma_f32_16x16x32_bf16(a[ai], bb[ci], acc[ai][ci], 0,0,0);
      }
    }
    __syncthreads();
  }

  if constexpr (!TR){
    float part[2][4];
    #pragma unroll
    for (int mi=0;mi<2;mi++){
      #pragma unroll
      for (int r=0;r<4;r++){
        float s=0.f;
        #pragma unroll
        for (int ni=0;ni<BF;ni++){ float v=acc[mi][ni][r]; s += v*v; }
        part[mi][r]=s;
      }
    }
    #pragma unroll
    for (int m=1;m<16;m<<=1){
      #pragma unroll
      for (int mi=0;mi<2;mi++){
        #pragma unroll
        for (int r=0;r<4;r++) part[mi][r] += __shfl_xor(part[mi][r], m);
      }
    }
    if (q16 == 0){
      #pragma unroll
      for (int mi=0;mi<2;mi++){
        #pragma unroll
        for (int r=0;r<4;r++) wsum[wid][16*mi + 4*g + r] = part[mi][r];
      }
    }
    __syncthreads();
    #pragma unroll
    for (int mi=0;mi<2;mi++){
      #pragma unroll
      for (int r=0;r<4;r++){
        int m = 16*mi + 4*g + r;
        float tot = wsum[0][m]+wsum[1][m]+wsum[2][m]+wsum[3][m];
        float inv = 1.f / fmaxf(sqrtf(tot), 1e-12f);
        #pragma unroll
        for (int ni=0;ni<BF;ni++){
          int col = wid*NW + 16*ni + q16;
          Y[(size_t)(row0+m)*ND + col] = f2bf(acc[mi][ni][r]*inv);
        }
      }
    }
  } else {
    float pp[2];
    #pragma unroll
    for (int ci=0;ci<2;ci++){
      float s=0.f;
      #pragma unroll
      for (int ai=0;ai<8;ai++){
        #pragma unroll
        for (int r=0;r<4;r++){ float v=acc[ai][ci][r]; s += v*v; }
      }
      pp[ci]=s;
    }
    #pragma unroll
    for (int ci=0;ci<2;ci++){
      pp[ci] += __shfl_xor(pp[ci],16);
      pp[ci] += __shfl_xor(pp[ci],32);
    }
    if (lane < 16){ wsum[wid][lane] = pp[0]; wsum[wid][16+lane] = pp[1]; }
    __syncthreads();
    #pragma unroll
    for (int ci=0;ci<2;ci++){
      int m = 16*ci + q16;
      float tot = wsum[0][m]+wsum[1][m]+wsum[2][m]+wsum[3][m];
      float inv = 1.f / fmaxf(sqrtf(tot), 1e-12f);
      int grow = row0 + m;
      int b = grow >> 11;
      int kv = grow & 2047;
      #pragma unroll
      for (int ai=0;ai<8;ai++){
        #pragma unroll
        for (int r=0;r<4;r++){
          int n = wid*NW + 16*ai + 4*g + r;
          Y[((size_t)b*FV + n)*NK + kv] = f2bf(acc[ai][ci][r]*inv);
        }
      }
    }
  }
}

// ---------------- fused attention (v3: 32x32 MFMA, in-reg P, fv-split) ----------------
// 512 blocks = 16 b x 8 qblk(256 q) x 4 fvblk(128 fv). 512 thr = 8 waves, q-slice 32/wave.
// S^T = mfma32(K, Q) per wave; fixed softmax max; P -> B-frag via cvt_pk + permlane32_swap;
// O^T = mfma32(Vt, P^T). Fragment-major LDS, contiguous lane*16 reads (conflict-free).
__global__ __launch_bounds__(512,2) void attn_kernel(const float* __restrict__ query,
    const unsigned short* __restrict__ wq, const unsigned short* __restrict__ wk,
    const unsigned short* __restrict__ wvt, float* __restrict__ out)
{
  // K dbuf 2x16K @0 | V dbuf 2x8K @32768 ; epilogue reuses [0, 33792)
  __shared__ __align__(16) char smem[49152];
  const int tid = threadIdx.x, lane = tid & 63, wid = tid >> 6;
  const int l31 = lane & 31, h = lane >> 5;
  const int bid = blockIdx.x;
  const int lb = (bid & 7)*64 + (bid >> 3);   // XCD chunk swizzle, 512 = 8*64 bijective
  const int b = lb >> 5;
  const int qblk = (lb >> 2) & 7;
  const int fvblk = lb & 3;
  const int q0 = qblk*256 + wid*32;           // wave's q rows: q0 + l31

  const char* wk_b  = (const char*)(wk  + (size_t)b*NK*D);
  const char* wvt_b = (const char*)(wvt + ((size_t)b*FV + fvblk*128)*NK);
  // K chunk c (c=2*wid,2*wid+1): lane l -> K[kv0 + l31][c*16 + h*8 ..+8]
  const char* ksrc = wk_b + (size_t)l31*512 + wid*64 + h*16;
  // V frag f=wid (ft=wid>>1, kt=wid&1): lane l -> Vt[ft*32 + l31][kv0 + kt*16 + h*8 ..+8]
  const char* vsrc = wvt_b + ((size_t)(wid>>1)*32 + l31)*4096 + (wid&1)*32 + h*16;

  #define STAGE(KV0, CUR) do{                                        \
    char* kb_ = smem + (CUR)*16384;                                  \
    char* vb_ = smem + 32768 + (CUR)*8192;                           \
    gload16(ksrc + (size_t)(KV0)*512,      kb_ + (2*wid  )*1024);    \
    gload16(ksrc + (size_t)(KV0)*512 + 32, kb_ + (2*wid+1)*1024);    \
    gload16(vsrc + (size_t)(KV0)*2,        vb_ + wid*1024);          \
  }while(0)

  STAGE(0, 0);

  // Q hoist: B-frags [16 d][32 q], lane: q=l31, d = c*16 + h*8 ..+8
  bf16x8 qf[16];
  {
    const char* qb = (const char*)(wq + ((size_t)b*NQ + q0 + l31)*D);
    #pragma unroll
    for (int c=0;c<16;c++) qf[c] = as_bf(*(const u32x4*)(qb + c*32 + h*16));
  }

  f32x16 z16;
  #pragma unroll
  for (int i=0;i<16;i++) z16[i]=0.f;
  f32x16 o[4];
  #pragma unroll
  for (int i=0;i<4;i++) o[i]=z16;
  float ssum = 0.f;
  const float c1 = 0.0625f * 1.44269504088896f;   // temp*log2(e)

  __syncthreads();

  for (int t = 0; t < 64; ++t){
    const int cur = t & 1;
    if (t < 63) STAGE((t+1)*32, cur^1);
    const char* kb = smem + cur*16384;
    const char* vb = smem + 32768 + cur*8192;

    // S^T[kv 32][q 32] = sum_c K-frag(c) x Q-frag(c)
    f32x16 S = z16;
    __builtin_amdgcn_s_setprio(1);
    #pragma unroll
    for (int c=0;c<16;c++){
      bf16x8 a = as_bf(*(const u32x4*)(kb + c*1024 + lane*16));
      S = __builtin_amdgcn_mfma_f32_32x32x16_bf16(a, qf[c], S, 0,0,0);
    }
    __builtin_amdgcn_s_setprio(0);

    // fixed-max softmax numerator (cosine logits <= 1/16): p = exp2((s-1)*c1)
    float p[16]; float part = 0.f;
    #pragma unroll
    for (int r=0;r<16;r++){ p[r] = exp2f((S[r]-1.0f)*c1); part += p[r]; }
    ssum += part;

    // P^T C/D regs -> PV B-frags in-register (T12): 8 cvt_pk + 4 permlane32_swap
    unsigned pk[8];
    #pragma unroll
    for (int j=0;j<8;j++) pk[j] = cvtpk(p[2*j], p[2*j+1]);
    plswap(pk[0], pk[2], h);   // f=0: w0={pk0.lo,pk2.lo}, w2={pk0.hi,pk2.hi}
    plswap(pk[1], pk[3], h);   //      w1, w3
    plswap(pk[4], pk[6], h);   // f=1
    plswap(pk[5], pk[7], h);
    u32x4 pw0 = {pk[0], pk[1], pk[2], pk[3]};
    u32x4 pw1 = {pk[4], pk[5], pk[6], pk[7]};
    bf16x8 pf0 = as_bf(pw0), pf1 = as_bf(pw1);

    // O^T[fv 128][q 32] += Vt-frag x P-frag
    __builtin_amdgcn_s_setprio(1);
    #pragma unroll
    for (int f=0; f<8; ++f){
      bf16x8 a = as_bf(*(const u32x4*)(vb + f*1024 + lane*16));
      o[f>>1] = __builtin_amdgcn_mfma_f32_32x32x16_bf16(a, (f&1)? pf1 : pf0, o[f>>1], 0,0,0);
    }
    __builtin_amdgcn_s_setprio(0);

    __syncthreads();
  }
  #undef STAGE

  // epilogue: scale, transpose via per-wave LDS chunk [8 q][132 f32], +query, store
  ssum += __shfl_xor(ssum, 32);
  float inv = 1.f/ssum;
  #pragma unroll
  for (int i=0;i<4;i++){
    #pragma unroll
    for (int r=0;r<16;r++) o[i][r] *= inv;
  }

  char* eb = smem + wid*4224;   // 8*132*4 = 4224 B per wave (post-barrier reuse)
  const int sub = l31 >> 3, qr = l31 & 7;
  const int rr = lane & 7, cc = lane >> 3;
  union U16 { f32x16 v; f32x4 q[4]; };
  #pragma unroll
  for (int a=0; a<4; ++a){
    if (sub == a){
      #pragma unroll
      for (int t2=0;t2<4;t2++){
        U16 u; u.v = o[t2];
        #pragma unroll
        for (int rq=0;rq<4;rq++){
          // fv_local = t2*32 + rq*8 + h*4 + e
          *(f32x4*)(eb + (qr*132 + t2*32 + rq*8 + h*4)*4) = u.q[rq];
        }
      }
    }
    __builtin_amdgcn_s_waitcnt(0);  // no-op safety; compiler orders lgkm anyway
    #pragma unroll
    for (int j=0;j<4;j++){
      f32x4 v = *(const f32x4*)(eb + (rr*132 + cc*16 + j*4)*4);
      int row = q0 + a*8 + rr;
      int col = fvblk*128 + cc*16 + j*4;
      const float* qp = query + ((size_t)b*NQ + row)*F + col;
      f32x4 qv = *(const f32x4*)qp;
      #pragma unroll
      for (int e=0;e<4;e++) v[e] += qv[e];
      *(f32x4*)(out + ((size_t)b*NQ + row)*F + col) = v;
    }
  }
}

extern "C" void kernel_launch(void* const* d_in, const int* in_sizes, int n_in,
                              void* d_out, int out_size, void* d_ws, size_t ws_size,
                              hipStream_t stream)
{
  const float* query = (const float*)d_in[0];
  const float* key   = (const float*)d_in[1];
  const float* value = (const float*)d_in[2];
  const float* WQ    = (const float*)d_in[3];
  const float* WK    = (const float*)d_in[4];
  const float* WV    = (const float*)d_in[5];
  float* out = (float*)d_out;

  unsigned short* wq  = (unsigned short*)d_ws;              // [B*NQ][256] bf16, 16MB
  unsigned short* wk  = wq + (size_t)BB*NQ*D;               // [B*NK][256] bf16, 16MB
  unsigned short* wvt = wk + (size_t)BB*NK*D;               // [B][512][NK] bf16, 32MB

  dim3 blk(256);
  proj_kernel<512,256,false><<<1024, blk, 0, stream>>>(query, WQ, wq);
  proj_kernel<256,256,false><<<1024, blk, 0, stream>>>(key,   WK, wk);
  proj_kernel<256,512,true ><<<1024, blk, 0, stream>>>(value, WV, wvt);
  attn_kernel<<<512, dim3(512), 0, stream>>>(query, wq, wk, wvt, out);
}